// Round 1
// baseline (310.365 us; speedup 1.0000x reference)
//
#include <hip/hip_runtime.h>

// NCA update: state (1024,1024,16) f32, channel-innermost.
// perc = [sobel_x(state), sobel_y(state), state]  (48 ch)
// hidden = relu(W1 @ perc + b1)   W1: (128,48)
// delta  = W2 @ hidden + b2       W2: (16,128)
// out (1024,1024,16) f32.

constexpr int Hc = 1024;
constexpr int Wc = 1024;
constexpr int Cc = 16;
constexpr int HID = 128;

__global__ __launch_bounds__(256) void nca_fp32(
    const float* __restrict__ state,
    const float* __restrict__ W1c,
    const float* __restrict__ b1c,
    const float* __restrict__ W2c,
    const float* __restrict__ b2c,
    float* __restrict__ out)
{
    const int idx = blockIdx.x * 256 + threadIdx.x;
    const int w = idx & (Wc - 1);
    const int h = idx >> 10;

    const int hm = (h - 1) & (Hc - 1);
    const int hp = (h + 1) & (Hc - 1);
    const int wm = (w - 1) & (Wc - 1);
    const int wp = (w + 1) & (Wc - 1);

    const float4* S = reinterpret_cast<const float4*>(state);

    const int r0 = hm * Wc;
    const int r1 = h * Wc;
    const int r2 = hp * Wc;

    float perc[48];

    // Load 3x3 neighborhood, 4 channels (one float4) at a time.
    #pragma unroll
    for (int q = 0; q < 4; ++q) {
        float v00[4], v01[4], v02[4];
        float v10[4], vcc[4], v12[4];
        float v20[4], v21[4], v22[4];
        *reinterpret_cast<float4*>(v00) = S[(r0 + wm) * 4 + q];
        *reinterpret_cast<float4*>(v01) = S[(r0 + w ) * 4 + q];
        *reinterpret_cast<float4*>(v02) = S[(r0 + wp) * 4 + q];
        *reinterpret_cast<float4*>(v10) = S[(r1 + wm) * 4 + q];
        *reinterpret_cast<float4*>(vcc) = S[(r1 + w ) * 4 + q];
        *reinterpret_cast<float4*>(v12) = S[(r1 + wp) * 4 + q];
        *reinterpret_cast<float4*>(v20) = S[(r2 + wm) * 4 + q];
        *reinterpret_cast<float4*>(v21) = S[(r2 + w ) * 4 + q];
        *reinterpret_cast<float4*>(v22) = S[(r2 + wp) * 4 + q];

        #pragma unroll
        for (int j = 0; j < 4; ++j) {
            const int c = q * 4 + j;
            // cross-correlation: weight[ky][kx] * in[h+ky-1][w+kx-1]
            // sobel_x = [[-1,0,1],[-2,0,2],[-1,0,1]]
            perc[c] = (v02[j] - v00[j]) + 2.f * (v12[j] - v10[j]) + (v22[j] - v20[j]);
            // sobel_y = [[-1,-2,-1],[0,0,0],[1,2,1]]
            perc[Cc + c] = (v20[j] + 2.f * v21[j] + v22[j])
                         - (v00[j] + 2.f * v01[j] + v02[j]);
            perc[2 * Cc + c] = vcc[j];
        }
    }

    // delta accumulators (init to b2); fuse layer-2 so hidden never materializes.
    float acc2[Cc];
    #pragma unroll
    for (int k = 0; k < Cc; ++k) acc2[k] = b2c[k];

    // All W1/W2/b1 indices are wave-uniform -> scalar loads (s_load), FMAs use
    // one SGPR operand + perc/acc in VGPRs. No LDS needed.
    #pragma unroll 2
    for (int o = 0; o < HID; ++o) {
        float a = b1c[o];
        #pragma unroll
        for (int c = 0; c < 48; ++c) {
            a = fmaf(W1c[o * 48 + c], perc[c], a);
        }
        const float hv = fmaxf(a, 0.f);
        #pragma unroll
        for (int k = 0; k < Cc; ++k) {
            acc2[k] = fmaf(W2c[k * HID + o], hv, acc2[k]);
        }
    }

    float4* O = reinterpret_cast<float4*>(out);
    #pragma unroll
    for (int q = 0; q < 4; ++q) {
        float t[4];
        #pragma unroll
        for (int j = 0; j < 4; ++j) t[j] = acc2[q * 4 + j];
        O[(r1 + w) * 4 + q] = *reinterpret_cast<const float4*>(t);
    }
}

extern "C" void kernel_launch(void* const* d_in, const int* in_sizes, int n_in,
                              void* d_out, int out_size, void* d_ws, size_t ws_size,
                              hipStream_t stream) {
    const float* state = (const float*)d_in[0];
    const float* W1c   = (const float*)d_in[1];
    const float* b1c   = (const float*)d_in[2];
    const float* W2c   = (const float*)d_in[3];
    const float* b2c   = (const float*)d_in[4];
    float* out = (float*)d_out;

    const int nthreads = Hc * Wc;
    nca_fp32<<<nthreads / 256, 256, 0, stream>>>(state, W1c, b1c, W2c, b2c, out);
}

// Round 2
// 188.761 us; speedup vs baseline: 1.6442x; 1.6442x over previous
//
#include <hip/hip_runtime.h>

// NCA update via bf16 MFMA, fully fused.
// state (1024,1024,16) f32 -> perc(48) -> relu(W1@perc+b1)(128) -> W2@h+b2 (16)
//
// Per wave: 16 pixels. Swapped GEMMs so pixel = MFMA column:
//   GEMM1: D1[hid][pix] = W1(16x64-tile) @ perc(64x16), K=64 (48 real + b1-fold at k=48)
//   GEMM2: D2[out][pix] = W2(16x128) @ hidden(128x16), K=128
// hidden is bounced through per-wave LDS (write D-layout, read B-frag layout).
// Fragment layout assumed (CDNA3/4 convention): A[row=l&15][k=8*(l>>4)+j],
// B[k=8*(l>>4)+j][col=l&15], D col=l&15, row=4*(l>>4)+reg (m89-verified).

constexpr int Hc = 1024, Wc = 1024;

typedef __attribute__((ext_vector_type(8))) short short8;
typedef __attribute__((ext_vector_type(4))) float f32x4;

__device__ __forceinline__ short f2bf(float x) {
    unsigned u = __builtin_bit_cast(unsigned, x);
    u += 0x7fffu + ((u >> 16) & 1u);   // round-to-nearest-even
    return (short)(u >> 16);
}

__device__ __forceinline__ void ld8(const float* __restrict__ base, float o[8]) {
    float4 a = *reinterpret_cast<const float4*>(base);
    float4 b = *reinterpret_cast<const float4*>(base + 4);
    o[0]=a.x; o[1]=a.y; o[2]=a.z; o[3]=a.w;
    o[4]=b.x; o[5]=b.y; o[6]=b.z; o[7]=b.w;
}

__global__ __launch_bounds__(256, 4) void nca_mfma(
    const float* __restrict__ state,
    const float* __restrict__ W1c,
    const float* __restrict__ b1c,
    const float* __restrict__ W2c,
    const float* __restrict__ b2c,
    float* __restrict__ out)
{
    // W1 as bf16, row-major [128][72] (cols 0..47 = W1, col 48 = b1, 49..63 = 0).
    // stride 72 shorts = 144 B -> ds_read_b128 across 16 rows is <=2-way banked.
    __shared__ short W1lds[128 * 72];
    // W2 bf16 [16][136] (cols 0..127 real). 272 B stride -> 2-way.
    __shared__ short W2lds[16 * 136];
    // hidden bf16, per wave: [16 pix][136 hid]. 272 B stride: b64 writes / b128
    // reads both 16B-aligned, 2-way banked (free).
    __shared__ short hidlds[4][16 * 136];

    const int tid = threadIdx.x;

    // ---- weights -> bf16 LDS (once per block) ----
    for (int i = tid; i < 128 * 64; i += 256) {
        const int row = i >> 6, c = i & 63;
        float v = (c < 48) ? W1c[row * 48 + c] : (c == 48 ? b1c[row] : 0.f);
        W1lds[row * 72 + c] = f2bf(v);
    }
    for (int i = tid; i < 16 * 128; i += 256) {
        const int row = i >> 7, c = i & 127;
        W2lds[row * 136 + c] = f2bf(W2c[row * 128 + c]);
    }
    __syncthreads();

    const int lane = tid & 63;
    const int wv   = tid >> 6;
    const int p    = lane & 15;   // pixel within wave / A-row / out-ch depending on role
    const int g    = lane >> 4;   // k-group

    const int pix = blockIdx.x * 64 + wv * 16 + p;
    const int h = pix >> 10, w = pix & (Wc - 1);
    const int hm = (h - 1) & (Hc - 1), hp = (h + 1) & (Hc - 1);
    const int wm = (w - 1) & (Wc - 1), wp = (w + 1) & (Wc - 1);
    const int co = (g & 1) * 8;   // channel offset (8 channels per k-group)

    // ---- perc B-fragments ----
    // chunk0 (k=0..31): g0: gx ch0-7, g1: gx ch8-15, g2: gy ch0-7, g3: gy ch8-15
    // chunk1 (k=32..63): g0: x ch0-7, g1: x ch8-15, g2: {1.0 (b1 fold), 0...}, g3: 0
    short8 bf0, bf1;
    {
        float pv[8];
        if (g < 2) {
            // sobel_x: sum over rows {hm,h,hp} w={1,2,1} of (col wp - col wm)
            float E[8], Wn[8];
            ld8(state + (((hm << 10) + wp) << 4) + co, E);
            ld8(state + (((hm << 10) + wm) << 4) + co, Wn);
            #pragma unroll
            for (int j = 0; j < 8; ++j) pv[j] = E[j] - Wn[j];
            ld8(state + (((h << 10) + wp) << 4) + co, E);
            ld8(state + (((h << 10) + wm) << 4) + co, Wn);
            #pragma unroll
            for (int j = 0; j < 8; ++j) pv[j] += 2.f * (E[j] - Wn[j]);
            ld8(state + (((hp << 10) + wp) << 4) + co, E);
            ld8(state + (((hp << 10) + wm) << 4) + co, Wn);
            #pragma unroll
            for (int j = 0; j < 8; ++j) pv[j] += E[j] - Wn[j];
        } else {
            // sobel_y: (row hp) - (row hm), cols {wm,w,wp} w={1,2,1}
            float S[8], N[8];
            ld8(state + (((hp << 10) + wm) << 4) + co, S);
            ld8(state + (((hm << 10) + wm) << 4) + co, N);
            #pragma unroll
            for (int j = 0; j < 8; ++j) pv[j] = S[j] - N[j];
            ld8(state + (((hp << 10) + w) << 4) + co, S);
            ld8(state + (((hm << 10) + w) << 4) + co, N);
            #pragma unroll
            for (int j = 0; j < 8; ++j) pv[j] += 2.f * (S[j] - N[j]);
            ld8(state + (((hp << 10) + wp) << 4) + co, S);
            ld8(state + (((hm << 10) + wp) << 4) + co, N);
            #pragma unroll
            for (int j = 0; j < 8; ++j) pv[j] += S[j] - N[j];
        }
        #pragma unroll
        for (int j = 0; j < 8; ++j) bf0[j] = f2bf(pv[j]);

        #pragma unroll
        for (int j = 0; j < 8; ++j) bf1[j] = 0;
        if (g < 2) {
            float x8[8];
            ld8(state + (((h << 10) + w) << 4) + co, x8);
            #pragma unroll
            for (int j = 0; j < 8; ++j) bf1[j] = f2bf(x8[j]);
        } else if (g == 2) {
            bf1[0] = (short)0x3F80;  // bf16 1.0 -> multiplies b1 at k=48
        }
    }

    // ---- GEMM1: 8 hidden tiles of 16; relu; stash bf16 hidden in LDS ----
    short* hrow = &hidlds[wv][0];
    #pragma unroll
    for (int t = 0; t < 8; ++t) {
        const short8 a0 = *reinterpret_cast<const short8*>(&W1lds[(16 * t + p) * 72 + 8 * g]);
        const short8 a1 = *reinterpret_cast<const short8*>(&W1lds[(16 * t + p) * 72 + 32 + 8 * g]);
        f32x4 acc = {0.f, 0.f, 0.f, 0.f};
        acc = __builtin_amdgcn_mfma_f32_16x16x32_bf16(a0, bf0, acc, 0, 0, 0);
        acc = __builtin_amdgcn_mfma_f32_16x16x32_bf16(a1, bf1, acc, 0, 0, 0);
        // D1: lane holds hidden rows 16t+4g+r (r=0..3) of pixel p. relu (b1 folded).
        unsigned lo = (unsigned short)f2bf(fmaxf(acc[0], 0.f))
                    | ((unsigned)(unsigned short)f2bf(fmaxf(acc[1], 0.f)) << 16);
        unsigned hi = (unsigned short)f2bf(fmaxf(acc[2], 0.f))
                    | ((unsigned)(unsigned short)f2bf(fmaxf(acc[3], 0.f)) << 16);
        uint2 u; u.x = lo; u.y = hi;
        *reinterpret_cast<uint2*>(&hrow[p * 136 + 16 * t + 4 * g]) = u;  // ds_write_b64
    }

    asm volatile("" ::: "memory");  // keep ds_writes above the reads below

    // ---- GEMM2: delta[16][16] = W2 @ hidden ----
    f32x4 acc2;
    {
        const float4 b2v = *reinterpret_cast<const float4*>(b2c + 4 * g);
        acc2[0] = b2v.x; acc2[1] = b2v.y; acc2[2] = b2v.z; acc2[3] = b2v.w;
    }
    #pragma unroll
    for (int kc = 0; kc < 4; ++kc) {
        const short8 wa = *reinterpret_cast<const short8*>(&W2lds[p * 136 + 32 * kc + 8 * g]);
        const short8 hb = *reinterpret_cast<const short8*>(&hrow[p * 136 + 32 * kc + 8 * g]);
        acc2 = __builtin_amdgcn_mfma_f32_16x16x32_bf16(wa, hb, acc2, 0, 0, 0);
    }

    // D2: lane holds out-ch 4g+r of pixel p -> 16B contiguous store.
    float4 o; o.x = acc2[0]; o.y = acc2[1]; o.z = acc2[2]; o.w = acc2[3];
    *reinterpret_cast<float4*>(out + (pix << 4) + 4 * g) = o;
}

extern "C" void kernel_launch(void* const* d_in, const int* in_sizes, int n_in,
                              void* d_out, int out_size, void* d_ws, size_t ws_size,
                              hipStream_t stream) {
    const float* state = (const float*)d_in[0];
    const float* W1c   = (const float*)d_in[1];
    const float* b1c   = (const float*)d_in[2];
    const float* W2c   = (const float*)d_in[3];
    const float* b2c   = (const float*)d_in[4];
    float* out = (float*)d_out;

    const int nblocks = (Hc * Wc) / 64;  // 64 pixels per block (4 waves x 16)
    nca_mfma<<<nblocks, 256, 0, stream>>>(state, W1c, b1c, W2c, b2c, out);
}

// Round 3
// 71.989 us; speedup vs baseline: 4.3113x; 2.6221x over previous
//
#include <hip/hip_runtime.h>

// NCA update, fully fused bf16-MFMA version.
//   out = W2 @ relu(Conv3x3(state; W1fold) + b1) + b2   per pixel
// where Conv3x3 folds sobel_x/sobel_y/identity into one 16->128 conv (K=144).
//
// Layout per block: 4 rows x 64 cols = 256 pixels. 4 waves, one row each.
// Wave: 4 pixel-tiles of 16. GEMM1: D1[hid][pix], A=W1fold (LDS), B=im2col
// from bf16 state tile (LDS). K=160 (144 real + b1-fold @k=144 + pad).
// GEMM2: D2[outch][pix], A=W2 (regs), B=hidden via in-register transpose
// (permlane32_swap + permlane16_swap), no hidden LDS bounce.
// Prep kernel precomputes bf16 W1fold[128][168] and W2[16][128] into d_ws.

constexpr int Hc = 1024, Wc = 1024;

typedef __attribute__((ext_vector_type(8))) short short8;
typedef __attribute__((ext_vector_type(4))) float f32x4;
typedef __attribute__((ext_vector_type(2))) unsigned int uint2v;

__device__ __forceinline__ unsigned short bfu(float x) {
    __bf16 b = (__bf16)x;                       // RNE, lowers to v_cvt_pk_bf16_f32
    return __builtin_bit_cast(unsigned short, b);
}
__device__ __forceinline__ unsigned pack2(float a, float b) {
    return (unsigned)bfu(a) | ((unsigned)bfu(b) << 16);
}

// swap32: o0 = [X(q0),X(q1),Y(q0),Y(q1)], o1 = [X(q2),X(q3),Y(q2),Y(q3)]  (q = 16-lane quarter)
__device__ __forceinline__ void swap32(unsigned x, unsigned y, unsigned& o0, unsigned& o1) {
#if __has_builtin(__builtin_amdgcn_permlane32_swap)
    uint2v r = __builtin_amdgcn_permlane32_swap(x, y, false, false);
    o0 = r[0]; o1 = r[1];
#else
    unsigned xs = (unsigned)__shfl_xor((int)x, 32, 64);
    unsigned ys = (unsigned)__shfl_xor((int)y, 32, 64);
    const bool hi = (threadIdx.x & 32) != 0;
    o0 = hi ? ys : x;
    o1 = hi ? y : xs;
#endif
}
// swap16: o0 = [A(q0),B(q0),A(q2),B(q2)], o1 = [A(q1),B(q1),A(q3),B(q3)]
__device__ __forceinline__ void swap16(unsigned a, unsigned b, unsigned& o0, unsigned& o1) {
#if __has_builtin(__builtin_amdgcn_permlane16_swap)
    uint2v r = __builtin_amdgcn_permlane16_swap(a, b, false, false);
    o0 = r[0]; o1 = r[1];
#else
    unsigned as = (unsigned)__shfl_xor((int)a, 16, 64);
    unsigned bs = (unsigned)__shfl_xor((int)b, 16, 64);
    const bool hi = (threadIdx.x & 16) != 0;
    o0 = hi ? bs : a;
    o1 = hi ? b : as;
#endif
}

// ---------------- prep: W1fold + W2 -> bf16 in ws ----------------
__global__ __launch_bounds__(256) void nca_prep(
    const float* __restrict__ W1c, const float* __restrict__ b1c,
    const float* __restrict__ W2c,
    unsigned short* __restrict__ ws1, unsigned short* __restrict__ ws2)
{
    const int u = blockIdx.x * 256 + threadIdx.x;
    if (u < 128 * 160) {
        const int row = u / 160, k = u - row * 160;
        const int pos = k >> 4, c = k & 15;
        float v;
        if (pos < 9) {
            const int dy = pos / 3, dx = pos - dy * 3;
            v = (float)((dx - 1) * (1 + (dy == 1))) * W1c[row * 48 + c]
              + (float)((dy - 1) * (1 + (dx == 1))) * W1c[row * 48 + 16 + c];
            if (pos == 4) v += W1c[row * 48 + 32 + c];
        } else {
            v = (k == 144) ? b1c[row] : 0.f;
        }
        ws1[row * 168 + k] = bfu(v);
    } else if (u < 128 * 160 + 16 * 128) {
        const int w = u - 128 * 160;
        ws2[w] = bfu(W2c[w]);
    }
}

// ---------------- main ----------------
template <bool USE_WS>
__global__ __launch_bounds__(256, 2) void nca_main(
    const float* __restrict__ state,
    const float* __restrict__ W1c, const float* __restrict__ b1c,
    const float* __restrict__ W2c, const float* __restrict__ b2c,
    const unsigned short* __restrict__ ws1,   // W1fold bf16 [128][168]
    const unsigned short* __restrict__ ws2,   // W2 bf16 [16][128]
    float* __restrict__ out)
{
    __shared__ short w1f[128 * 168];          // 43008 B, row stride 336 B
    __shared__ short tile[6 * 66 * 24];       // 19008 B, pixel stride 48 B

    const int tid  = threadIdx.x;
    const int lane = tid & 63;
    const int wv   = tid >> 6;
    const int p    = lane & 15;
    const int g    = lane >> 4;

    const int r0 = (blockIdx.x >> 4) << 2;    // 256 row-groups of 4
    const int c0 = (blockIdx.x & 15) << 6;    // 16 col-groups of 64

    // ---- stage W1fold into LDS ----
    if (USE_WS) {
        #pragma unroll
        for (int it = 0; it < 11; ++it) {
            const int chunk = it * 4 + wv;              // 42 x 1KB chunks
            if (chunk < 42) {
                const int off = chunk * 1024;
                __builtin_amdgcn_global_load_lds(
                    (const __attribute__((address_space(1))) unsigned int*)
                        ((const char*)ws1 + off + lane * 16),
                    (__attribute__((address_space(3))) unsigned int*)
                        ((char*)w1f + off),
                    16, 0, 0);
            }
        }
    } else {
        for (int u = tid; u < 128 * 160; u += 256) {
            const int row = u / 160, k = u - row * 160;
            const int pos = k >> 4, c = k & 15;
            float v;
            if (pos < 9) {
                const int dy = pos / 3, dx = pos - dy * 3;
                v = (float)((dx - 1) * (1 + (dy == 1))) * W1c[row * 48 + c]
                  + (float)((dy - 1) * (1 + (dx == 1))) * W1c[row * 48 + 16 + c];
                if (pos == 4) v += W1c[row * 48 + 32 + c];
            } else {
                v = (k == 144) ? b1c[row] : 0.f;
            }
            w1f[row * 168 + k] = (short)bfu(v);
        }
    }

    // ---- stage state tile (6 rows x 66 cols x 16 ch) as bf16 ----
    for (int u = tid; u < 6 * 66 * 4; u += 256) {
        const int q = u & 3;
        const int pidx = u >> 2;
        const int tr = pidx / 66, tc = pidx - tr * 66;
        const int sr = (r0 - 1 + tr) & (Hc - 1);
        const int sc = (c0 - 1 + tc) & (Wc - 1);
        const float4 f = *reinterpret_cast<const float4*>(
            state + (((sr << 10) + sc) << 4) + 4 * q);
        uint2 pk; pk.x = pack2(f.x, f.y); pk.y = pack2(f.z, f.w);
        *reinterpret_cast<uint2*>(&tile[pidx * 24 + 4 * q]) = pk;
    }

    __syncthreads();

    // ---- W2 A-fragments (kept in registers) ----
    short8 w2f[4];
    if (USE_WS) {
        const unsigned short* wsp = ws2 + p * 128 + 8 * g;
        #pragma unroll
        for (int kc = 0; kc < 4; ++kc)
            w2f[kc] = *reinterpret_cast<const short8*>(wsp + 32 * kc);
    } else {
        #pragma unroll
        for (int kc = 0; kc < 4; ++kc) {
            const float* qp = W2c + p * 128 + 32 * kc + 8 * g;
            const float4 A = *reinterpret_cast<const float4*>(qp);
            const float4 B = *reinterpret_cast<const float4*>(qp + 4);
            uint4 uu{pack2(A.x, A.y), pack2(A.z, A.w), pack2(B.x, B.y), pack2(B.z, B.w)};
            w2f[kc] = __builtin_bit_cast(short8, uu);
        }
    }

    // ---- B1 (im2col) fragments: 5 k-chunks x 4 pixel-tiles ----
    int baddr[5];
    #pragma unroll
    for (int i = 0; i < 5; ++i) {
        int j = 4 * i + g; if (j > 17) j = 17;
        const int pos = j >> 1, ch = j & 1;
        const int dy = pos / 3, dx = pos - dy * 3;
        baddr[i] = ((wv + dy) * 66 + p + dx) * 24 + 8 * ch;   // short index
    }
    short8 b1f[4][5];
    #pragma unroll
    for (int pt = 0; pt < 4; ++pt) {
        #pragma unroll
        for (int i = 0; i < 4; ++i)
            b1f[pt][i] = *reinterpret_cast<const short8*>(&tile[baddr[i] + pt * 384]);
        short8 v;
        if (g < 2) {
            v = *reinterpret_cast<const short8*>(&tile[baddr[4] + pt * 384]);
        } else if (g == 2) {
            uint4 uu{0x3F80u, 0u, 0u, 0u};                    // bf16 1.0 @ k=144 (b1 fold)
            v = __builtin_bit_cast(short8, uu);
        } else {
            uint4 uu{0u, 0u, 0u, 0u};
            v = __builtin_bit_cast(short8, uu);
        }
        b1f[pt][4] = v;
    }

    // ---- accumulators for GEMM2 (b2 init) ----
    f32x4 acc2[4];
    {
        const float4 bv = *reinterpret_cast<const float4*>(b2c + 4 * g);
        #pragma unroll
        for (int pt = 0; pt < 4; ++pt) {
            acc2[pt][0] = bv.x; acc2[pt][1] = bv.y; acc2[pt][2] = bv.z; acc2[pt][3] = bv.w;
        }
    }

    const int abase = p * 168 + 8 * g;        // short index into w1f
    #pragma unroll
    for (int kc2 = 0; kc2 < 4; ++kc2) {
        f32x4 aa[4], ab[4];
        #pragma unroll
        for (int pt = 0; pt < 4; ++pt) {
            aa[pt] = (f32x4){0.f, 0.f, 0.f, 0.f};
            ab[pt] = (f32x4){0.f, 0.f, 0.f, 0.f};
        }
        // hidden tile t = 2*kc2
        #pragma unroll
        for (int i = 0; i < 5; ++i) {
            const short8 A = *reinterpret_cast<const short8*>(
                &w1f[abase + (2 * kc2) * 2688 + 32 * i]);
            #pragma unroll
            for (int pt = 0; pt < 4; ++pt)
                aa[pt] = __builtin_amdgcn_mfma_f32_16x16x32_bf16(A, b1f[pt][i], aa[pt], 0, 0, 0);
        }
        // hidden tile t = 2*kc2 + 1
        #pragma unroll
        for (int i = 0; i < 5; ++i) {
            const short8 A = *reinterpret_cast<const short8*>(
                &w1f[abase + (2 * kc2 + 1) * 2688 + 32 * i]);
            #pragma unroll
            for (int pt = 0; pt < 4; ++pt)
                ab[pt] = __builtin_amdgcn_mfma_f32_16x16x32_bf16(A, b1f[pt][i], ab[pt], 0, 0, 0);
        }
        // relu -> bf16 pack -> in-register transpose -> GEMM2 chunk kc2
        #pragma unroll
        for (int pt = 0; pt < 4; ++pt) {
            const unsigned Pa0 = pack2(fmaxf(aa[pt][0], 0.f), fmaxf(aa[pt][1], 0.f));
            const unsigned Pa1 = pack2(fmaxf(aa[pt][2], 0.f), fmaxf(aa[pt][3], 0.f));
            const unsigned Pb0 = pack2(fmaxf(ab[pt][0], 0.f), fmaxf(ab[pt][1], 0.f));
            const unsigned Pb1 = pack2(fmaxf(ab[pt][2], 0.f), fmaxf(ab[pt][3], 0.f));
            unsigned s0, s1, t0, t1, r0_, r1_, r2_, r3_;
            swap32(Pa0, Pb0, s0, s1);
            swap16(s0, s1, r0_, r2_);
            swap32(Pa1, Pb1, t0, t1);
            swap16(t0, t1, r1_, r3_);
            uint4 uu{r0_, r1_, r2_, r3_};
            const short8 hb = __builtin_bit_cast(short8, uu);
            acc2[pt] = __builtin_amdgcn_mfma_f32_16x16x32_bf16(w2f[kc2], hb, acc2[pt], 0, 0, 0);
        }
    }

    // ---- store: lane (p,g) holds out-ch 4g..4g+3 of its 4 pixels ----
    const int orow = r0 + wv;
    #pragma unroll
    for (int pt = 0; pt < 4; ++pt) {
        const int pix = (orow << 10) + c0 + 16 * pt + p;
        float4 o; o.x = acc2[pt][0]; o.y = acc2[pt][1]; o.z = acc2[pt][2]; o.w = acc2[pt][3];
        *reinterpret_cast<float4*>(out + (pix << 4) + 4 * g) = o;
    }
}

extern "C" void kernel_launch(void* const* d_in, const int* in_sizes, int n_in,
                              void* d_out, int out_size, void* d_ws, size_t ws_size,
                              hipStream_t stream) {
    const float* state = (const float*)d_in[0];
    const float* W1c   = (const float*)d_in[1];
    const float* b1c   = (const float*)d_in[2];
    const float* W2c   = (const float*)d_in[3];
    const float* b2c   = (const float*)d_in[4];
    float* out = (float*)d_out;

    unsigned short* ws1 = (unsigned short*)d_ws;
    unsigned short* ws2 = ws1 + 128 * 168;
    const size_t ws_needed = (size_t)(128 * 168 + 16 * 128) * sizeof(unsigned short);

    if (ws_size >= ws_needed) {
        nca_prep<<<88, 256, 0, stream>>>(W1c, b1c, W2c, ws1, ws2);
        nca_main<true><<<4096, 256, 0, stream>>>(state, W1c, b1c, W2c, b2c, ws1, ws2, out);
    } else {
        nca_main<false><<<4096, 256, 0, stream>>>(state, W1c, b1c, W2c, b2c, ws1, ws2, out);
    }
}

// Round 4
// 65.454 us; speedup vs baseline: 4.7417x; 1.0998x over previous
//
#include <hip/hip_runtime.h>

// NCA update, fused bf16-MFMA, pipelined multi-tile persistent blocks.
//   out = W2 @ relu(Conv3x3(state; W1fold) + b1) + b2
// W1fold folds sobel_x/sobel_y/identity into a 16->128 3x3 conv (K=144,
// b1 folded at k=144, padded to 160). Prep kernel emits bf16 W1fold/W2 to ws.
//
// Grid: 512 blocks (exactly 2/CU), each handles 8 tiles of 4rows x 64cols
// (a 32x64 region). W1fold staged to LDS once per block via global_load_lds.
// Per tile: T14 split staging (issue loads -> compute -> cvt+ds_write ->
// barrier), double-buffered bf16 state tile in LDS.
// Compute per wave (one tile row, 64 px): A-fragments held in registers
// (half of W1fold at a time, 80 VGPR), B read once per (pt,i) -> LDS read
// traffic ~80 b128/wave/tile (was ~200). Hidden transposed in-register via
// permlane32/16_swap, GEMM2 fused, no hidden LDS bounce.

constexpr int Hc = 1024, Wc = 1024;

typedef __attribute__((ext_vector_type(8))) short short8;
typedef __attribute__((ext_vector_type(4))) float f32x4;
typedef __attribute__((ext_vector_type(2))) unsigned int uint2v;

__device__ __forceinline__ unsigned short bfu(float x) {
    __bf16 b = (__bf16)x;                       // RNE
    return __builtin_bit_cast(unsigned short, b);
}
__device__ __forceinline__ unsigned pack2(float a, float b) {
    return (unsigned)bfu(a) | ((unsigned)bfu(b) << 16);
}

__device__ __forceinline__ void swap32(unsigned x, unsigned y, unsigned& o0, unsigned& o1) {
#if __has_builtin(__builtin_amdgcn_permlane32_swap)
    uint2v r = __builtin_amdgcn_permlane32_swap(x, y, false, false);
    o0 = r[0]; o1 = r[1];
#else
    unsigned xs = (unsigned)__shfl_xor((int)x, 32, 64);
    unsigned ys = (unsigned)__shfl_xor((int)y, 32, 64);
    const bool hi = (threadIdx.x & 32) != 0;
    o0 = hi ? ys : x;
    o1 = hi ? y : xs;
#endif
}
__device__ __forceinline__ void swap16(unsigned a, unsigned b, unsigned& o0, unsigned& o1) {
#if __has_builtin(__builtin_amdgcn_permlane16_swap)
    uint2v r = __builtin_amdgcn_permlane16_swap(a, b, false, false);
    o0 = r[0]; o1 = r[1];
#else
    unsigned as = (unsigned)__shfl_xor((int)a, 16, 64);
    unsigned bs = (unsigned)__shfl_xor((int)b, 16, 64);
    const bool hi = (threadIdx.x & 16) != 0;
    o0 = hi ? bs : a;
    o1 = hi ? b : as;
#endif
}

// ---------------- prep: W1fold + W2 -> bf16 in ws ----------------
__global__ __launch_bounds__(256) void nca_prep(
    const float* __restrict__ W1c, const float* __restrict__ b1c,
    const float* __restrict__ W2c,
    unsigned short* __restrict__ ws1, unsigned short* __restrict__ ws2)
{
    const int u = blockIdx.x * 256 + threadIdx.x;
    if (u < 128 * 160) {
        const int row = u / 160, k = u - row * 160;
        const int pos = k >> 4, c = k & 15;
        float v;
        if (pos < 9) {
            const int dy = pos / 3, dx = pos - dy * 3;
            v = (float)((dx - 1) * (1 + (dy == 1))) * W1c[row * 48 + c]
              + (float)((dy - 1) * (1 + (dx == 1))) * W1c[row * 48 + 16 + c];
            if (pos == 4) v += W1c[row * 48 + 32 + c];
        } else {
            v = (k == 144) ? b1c[row] : 0.f;
        }
        ws1[row * 168 + k] = bfu(v);
    } else if (u < 128 * 160 + 16 * 128) {
        const int w = u - 128 * 160;
        ws2[w] = bfu(W2c[w]);
    }
}

// ---------------- main ----------------
template <bool USE_WS>
__global__ __launch_bounds__(256, 2) void nca_main(
    const float* __restrict__ state,
    const float* __restrict__ W1c, const float* __restrict__ b1c,
    const float* __restrict__ W2c, const float* __restrict__ b2c,
    const unsigned short* __restrict__ ws1,   // W1fold bf16 [128][168]
    const unsigned short* __restrict__ ws2,   // W2 bf16 [16][128]
    float* __restrict__ out)
{
    __shared__ short w1f[128 * 168];          // 43008 B
    __shared__ short tile[2][6 * 66 * 24];    // 2 x 19008 B  (total 81024 B -> 2 blk/CU)

    const int tid  = threadIdx.x;
    const int lane = tid & 63;
    const int wv   = tid >> 6;
    const int p    = lane & 15;
    const int g    = lane >> 4;

    const int r0 = (blockIdx.x >> 4) << 5;    // 32 row-groups of 32 rows
    const int c0 = (blockIdx.x & 15) << 6;    // 16 col-groups of 64

    // ---- W1fold -> LDS (once per block) ----
    if (USE_WS) {
        #pragma unroll
        for (int it = 0; it < 11; ++it) {
            const int chunk = it * 4 + wv;              // 42 x 1KB chunks
            if (chunk < 42) {
                const int off = chunk * 1024;
                __builtin_amdgcn_global_load_lds(
                    (const __attribute__((address_space(1))) unsigned int*)
                        ((const char*)ws1 + off + lane * 16),
                    (__attribute__((address_space(3))) unsigned int*)
                        ((char*)w1f + off),
                    16, 0, 0);
            }
        }
    } else {
        for (int u = tid; u < 128 * 160; u += 256) {
            const int row = u / 160, k = u - row * 160;
            const int pos = k >> 4, c = k & 15;
            float v;
            if (pos < 9) {
                const int dy = pos / 3, dx = pos - dy * 3;
                v = (float)((dx - 1) * (1 + (dy == 1))) * W1c[row * 48 + c]
                  + (float)((dy - 1) * (1 + (dx == 1))) * W1c[row * 48 + 16 + c];
                if (pos == 4) v += W1c[row * 48 + 32 + c];
            } else {
                v = (k == 144) ? b1c[row] : 0.f;
            }
            w1f[row * 168 + k] = (short)bfu(v);
        }
    }

    // ---- per-thread staging constants (1584 float4 chunks = 256*6 + 48) ----
    const int q = tid & 3;
    int str_[7], sgofs[7], slofs[7];
    #pragma unroll
    for (int s = 0; s < 7; ++s) {
        const int pidx = (tid >> 2) + 64 * s;          // pixel index in 6x66 tile
        const int tr = pidx / 66;
        const int tc = pidx - tr * 66;
        str_[s]  = tr;
        sgofs[s] = (((c0 - 1 + tc) & (Wc - 1)) << 6) + (q << 4);   // bytes in row
        slofs[s] = pidx * 48 + (q << 3);                            // LDS bytes
    }
    const bool has7 = (tid < 48);

    // ---- W2 fragments + b2 (registers) ----
    short8 w2f[4];
    if (USE_WS) {
        const unsigned short* wsp = ws2 + p * 128 + 8 * g;
        #pragma unroll
        for (int kc = 0; kc < 4; ++kc)
            w2f[kc] = *reinterpret_cast<const short8*>(wsp + 32 * kc);
    } else {
        #pragma unroll
        for (int kc = 0; kc < 4; ++kc) {
            const float* qp = W2c + p * 128 + 32 * kc + 8 * g;
            const float4 A = *reinterpret_cast<const float4*>(qp);
            const float4 B = *reinterpret_cast<const float4*>(qp + 4);
            uint4 uu{pack2(A.x, A.y), pack2(A.z, A.w), pack2(B.x, B.y), pack2(B.z, B.w)};
            w2f[kc] = __builtin_bit_cast(short8, uu);
        }
    }
    const float4 bv = *reinterpret_cast<const float4*>(b2c + 4 * g);

    // ---- im2col B base addrs (short idx), constant per block ----
    int baddr[5];
    #pragma unroll
    for (int i = 0; i < 5; ++i) {
        int j = 4 * i + g; if (j > 17) j = 17;
        const int pos = j >> 1, ch = j & 1;
        const int dy = pos / 3, dx = pos - dy * 3;
        baddr[i] = ((wv + dy) * 66 + p + dx) * 24 + 8 * ch;
    }
    const int abase = p * 168 + 8 * g;

    // output column parts (bytes)
    int ocol[4];
    #pragma unroll
    for (int pt = 0; pt < 4; ++pt) ocol[pt] = ((c0 + 16 * pt + p) << 6) + (g << 4);

    const char* stby = (const char*)state;
    char* outby = (char*)out;

    // ---- prologue: stage tile 0 ----
    {
        float4 sreg[7];
        const int rb = r0 - 1;
        #pragma unroll
        for (int s = 0; s < 7; ++s) {
            if (s < 6 || has7) {
                const long sr = (long)((rb + str_[s]) & (Hc - 1));
                sreg[s] = *reinterpret_cast<const float4*>(stby + (sr << 16) + sgofs[s]);
            }
        }
        short* wb = &tile[0][0];
        #pragma unroll
        for (int s = 0; s < 7; ++s) {
            if (s < 6 || has7) {
                uint2 pk; pk.x = pack2(sreg[s].x, sreg[s].y); pk.y = pack2(sreg[s].z, sreg[s].w);
                *reinterpret_cast<uint2*>((char*)wb + slofs[s]) = pk;
            }
        }
    }
    __syncthreads();

    // ---- 8 tiles, software-pipelined ----
    #pragma unroll 2
    for (int t = 0; t < 8; ++t) {
        // (a) issue next tile's global loads into registers
        float4 sreg[7];
        if (t < 7) {
            const int rb = r0 + 4 * (t + 1) - 1;
            #pragma unroll
            for (int s = 0; s < 7; ++s) {
                if (s < 6 || has7) {
                    const long sr = (long)((rb + str_[s]) & (Hc - 1));
                    sreg[s] = *reinterpret_cast<const float4*>(stby + (sr << 16) + sgofs[s]);
                }
            }
        }

        // (b) compute current tile
        const short* tb = &tile[t & 1][0];
        f32x4 acc2[4];
        #pragma unroll
        for (int pt = 0; pt < 4; ++pt) {
            acc2[pt][0] = bv.x; acc2[pt][1] = bv.y; acc2[pt][2] = bv.z; acc2[pt][3] = bv.w;
        }

        #pragma unroll
        for (int half = 0; half < 2; ++half) {
            short8 Ar[4][5];   // 4 hidden-tiles x 5 k-chunks, resident
            #pragma unroll
            for (int tt = 0; tt < 4; ++tt) {
                #pragma unroll
                for (int i = 0; i < 5; ++i) {
                    Ar[tt][i] = *reinterpret_cast<const short8*>(
                        &w1f[abase + (64 * half + 16 * tt) * 168 + 32 * i]);
                }
            }

            #pragma unroll
            for (int pt = 0; pt < 4; ++pt) {
                f32x4 h[4];
                #pragma unroll
                for (int tt = 0; tt < 4; ++tt) h[tt] = (f32x4){0.f, 0.f, 0.f, 0.f};

                #pragma unroll
                for (int i = 0; i < 5; ++i) {
                    short8 B;
                    if (i < 4) {
                        B = *reinterpret_cast<const short8*>(&tb[baddr[i] + pt * 384]);
                    } else {
                        if (g < 2) {
                            B = *reinterpret_cast<const short8*>(&tb[baddr[4] + pt * 384]);
                        } else if (g == 2) {
                            uint4 uu{0x3F80u, 0u, 0u, 0u};     // bf16 1.0 @ k=144 (b1)
                            B = __builtin_bit_cast(short8, uu);
                        } else {
                            uint4 uu{0u, 0u, 0u, 0u};
                            B = __builtin_bit_cast(short8, uu);
                        }
                    }
                    #pragma unroll
                    for (int tt = 0; tt < 4; ++tt)
                        h[tt] = __builtin_amdgcn_mfma_f32_16x16x32_bf16(Ar[tt][i], B, h[tt], 0, 0, 0);
                }

                // relu -> pack -> in-register transpose -> GEMM2
                #pragma unroll
                for (int pr = 0; pr < 2; ++pr) {
                    const f32x4 ha = h[2 * pr], hc = h[2 * pr + 1];
                    const unsigned Pa0 = pack2(fmaxf(ha[0], 0.f), fmaxf(ha[1], 0.f));
                    const unsigned Pa1 = pack2(fmaxf(ha[2], 0.f), fmaxf(ha[3], 0.f));
                    const unsigned Pb0 = pack2(fmaxf(hc[0], 0.f), fmaxf(hc[1], 0.f));
                    const unsigned Pb1 = pack2(fmaxf(hc[2], 0.f), fmaxf(hc[3], 0.f));
                    unsigned s0, s1, t0, t1, u0, u1, u2, u3;
                    swap32(Pa0, Pb0, s0, s1);
                    swap16(s0, s1, u0, u2);
                    swap32(Pa1, Pb1, t0, t1);
                    swap16(t0, t1, u1, u3);
                    uint4 uu{u0, u1, u2, u3};
                    const short8 hbf = __builtin_bit_cast(short8, uu);
                    acc2[pt] = __builtin_amdgcn_mfma_f32_16x16x32_bf16(
                        w2f[2 * half + pr], hbf, acc2[pt], 0, 0, 0);
                }
            }
        }

        // (c) store output
        const long orow = (long)(r0 + 4 * t + wv) << 16;
        #pragma unroll
        for (int pt = 0; pt < 4; ++pt) {
            float4 o; o.x = acc2[pt][0]; o.y = acc2[pt][1]; o.z = acc2[pt][2]; o.w = acc2[pt][3];
            *reinterpret_cast<float4*>(outby + orow + ocol[pt]) = o;
        }

        // (d) convert + write next tile into other buffer, then barrier
        if (t < 7) {
            short* wb = &tile[(t + 1) & 1][0];
            #pragma unroll
            for (int s = 0; s < 7; ++s) {
                if (s < 6 || has7) {
                    uint2 pk; pk.x = pack2(sreg[s].x, sreg[s].y); pk.y = pack2(sreg[s].z, sreg[s].w);
                    *reinterpret_cast<uint2*>((char*)wb + slofs[s]) = pk;
                }
            }
        }
        __syncthreads();
    }
}

extern "C" void kernel_launch(void* const* d_in, const int* in_sizes, int n_in,
                              void* d_out, int out_size, void* d_ws, size_t ws_size,
                              hipStream_t stream) {
    const float* state = (const float*)d_in[0];
    const float* W1c   = (const float*)d_in[1];
    const float* b1c   = (const float*)d_in[2];
    const float* W2c   = (const float*)d_in[3];
    const float* b2c   = (const float*)d_in[4];
    float* out = (float*)d_out;

    unsigned short* ws1 = (unsigned short*)d_ws;
    unsigned short* ws2 = ws1 + 128 * 168;
    const size_t ws_needed = (size_t)(128 * 168 + 16 * 128) * sizeof(unsigned short);

    if (ws_size >= ws_needed) {
        nca_prep<<<88, 256, 0, stream>>>(W1c, b1c, W2c, ws1, ws2);
        nca_main<true><<<512, 256, 0, stream>>>(state, W1c, b1c, W2c, b2c, ws1, ws2, out);
    } else {
        nca_main<false><<<512, 256, 0, stream>>>(state, W1c, b1c, W2c, b2c, ws1, ws2, out);
    }
}